// Round 2
// baseline (481.580 us; speedup 1.0000x reference)
//
#include <hip/hip_runtime.h>
#include <math.h>

#define T_SEQ 2048
#define C_DIM 2048
#define NH    16
#define NG    4
#define DH    128
#define BATCH 2

typedef unsigned short u16;
typedef __bf16 bf16_t;
typedef bf16_t bf16x8 __attribute__((ext_vector_type(8)));
typedef float  f32x4  __attribute__((ext_vector_type(4)));

static __device__ __forceinline__ u16 f2bf(float f) {
    return __builtin_bit_cast(u16, (__bf16)f);
}

// async global->LDS, 16B per lane. lds must be wave-uniform base; HW adds lane*16.
static __device__ __forceinline__ void gll16(const void* g, void* lds) {
    __builtin_amdgcn_global_load_lds(
        (const __attribute__((address_space(1))) void*)(unsigned long long)(g),
        (__attribute__((address_space(3))) void*)(unsigned int)(unsigned long long)(lds),
        16, 0, 0);
}

// ---------------------------------------------------------------------------
// fused fp32->bf16 cast for x, Wq, Wk, Wv (8 elems/thread, flat if-chain)
// chunk counts: x 1048576 | Wq 524288 | Wk 131072 | Wv 131072  (sum = 7168*256)
// ---------------------------------------------------------------------------
__global__ __launch_bounds__(256)
void cast_multi(const float* __restrict__ x,  const float* __restrict__ wq,
                const float* __restrict__ wk, const float* __restrict__ wv,
                u16* __restrict__ xo, u16* __restrict__ wqo,
                u16* __restrict__ wko, u16* __restrict__ wvo) {
    int i = blockIdx.x * 256 + threadIdx.x;
    const float* src; u16* dst; int off;
    if (i < 1048576)      { src = x;  dst = xo;  off = i; }
    else if (i < 1572864) { src = wq; dst = wqo; off = i - 1048576; }
    else if (i < 1703936) { src = wk; dst = wko; off = i - 1572864; }
    else                  { src = wv; dst = wvo; off = i - 1703936; }
    const float4* p = (const float4*)src + (size_t)off * 2;
    float4 a = p[0], b = p[1];
    u16 u[8] = {f2bf(a.x), f2bf(a.y), f2bf(a.z), f2bf(a.w),
                f2bf(b.x), f2bf(b.y), f2bf(b.z), f2bf(b.w)};
    *(uint4*)(dst + (size_t)off * 8) = *(const uint4*)u;
}

__global__ __launch_bounds__(256)
void cast_f32_bf16(const float* __restrict__ in, u16* __restrict__ out, int n8) {
    int i = blockIdx.x * 256 + threadIdx.x;
    if (i >= n8) return;
    const float4* p = (const float4*)in + (size_t)i * 2;
    float4 a = p[0], b = p[1];
    u16 u[8] = {f2bf(a.x), f2bf(a.y), f2bf(a.z), f2bf(a.w),
                f2bf(b.x), f2bf(b.y), f2bf(b.z), f2bf(b.w)};
    *(uint4*)(out + (size_t)i * 8) = *(const uint4*)u;
}

// ---------------------------------------------------------------------------
// C(fp32, M x N) = A_bf16(M,K) @ B_bf16(N,K)^T (+bias)
// 128x128 tile, BK=32, 4 waves, each wave 64x64 (4x4 MFMA 16x16x32).
// ---------------------------------------------------------------------------
static __device__ __forceinline__ void gemm_body(
        u16* As, u16* Bs,
        const u16* __restrict__ A, const u16* __restrict__ B,
        const float* __restrict__ bias, float* __restrict__ C,
        int N, int K, int m0, int n0) {
    const int t    = threadIdx.x;
    const int lane = t & 63, w = t >> 6;
    const int l15  = lane & 15, quad = lane >> 4;
    const int wr   = w >> 1, wc = w & 1;

    f32x4 acc[4][4];
#pragma unroll
    for (int mt = 0; mt < 4; ++mt)
#pragma unroll
        for (int nt = 0; nt < 4; ++nt) acc[mt][nt] = (f32x4){0.f, 0.f, 0.f, 0.f};

    const int off0 = w*2048 + lane*16;
    const int r0 = off0 >> 6,          c0 = (off0 & 63) >> 1;
    const int r1 = (off0+1024) >> 6,   c1 = ((off0+1024) & 63) >> 1;
    const u16* Ag0 = A + (size_t)(m0 + r0) * K + c0;
    const u16* Ag1 = A + (size_t)(m0 + r1) * K + c1;
    const u16* Bg0 = B + (size_t)(n0 + r0) * K + c0;
    const u16* Bg1 = B + (size_t)(n0 + r1) * K + c1;
    char* AsB = (char*)As; char* BsB = (char*)Bs;
    const int ldsOff0 = w*2048, ldsOff1 = w*2048 + 1024;

    for (int k0 = 0; k0 < K; k0 += 32) {
        gll16(Ag0 + k0, AsB + ldsOff0);
        gll16(Ag1 + k0, AsB + ldsOff1);
        gll16(Bg0 + k0, BsB + ldsOff0);
        gll16(Bg1 + k0, BsB + ldsOff1);
        __syncthreads();
        bf16x8 af[4], bf[4];
#pragma unroll
        for (int mt = 0; mt < 4; ++mt)
            af[mt] = __builtin_bit_cast(bf16x8,
                *(const uint4*)&As[(wr*64 + mt*16 + l15)*32 + quad*8]);
#pragma unroll
        for (int nt = 0; nt < 4; ++nt)
            bf[nt] = __builtin_bit_cast(bf16x8,
                *(const uint4*)&Bs[(wc*64 + nt*16 + l15)*32 + quad*8]);
#pragma unroll
        for (int mt = 0; mt < 4; ++mt)
#pragma unroll
            for (int nt = 0; nt < 4; ++nt)
                acc[mt][nt] = __builtin_amdgcn_mfma_f32_16x16x32_bf16(
                                  af[mt], bf[nt], acc[mt][nt], 0, 0, 0);
        __syncthreads();
    }

#pragma unroll
    for (int mt = 0; mt < 4; ++mt)
#pragma unroll
        for (int nt = 0; nt < 4; ++nt) {
            const int col = n0 + wc*64 + nt*16 + l15;
            const float bv = bias ? bias[col] : 0.f;
#pragma unroll
            for (int r = 0; r < 4; ++r) {
                const int row = m0 + wr*64 + mt*16 + quad*4 + r;
                C[(size_t)row * N + col] = acc[mt][nt][r] + bv;
            }
        }
}

__global__ __launch_bounds__(256)
void gemm_nt_bf16(const u16* __restrict__ A, const u16* __restrict__ B,
                  const float* __restrict__ bias, float* __restrict__ C,
                  int N, int K) {
    __shared__ __align__(16) u16 As[128*32];
    __shared__ __align__(16) u16 Bs[128*32];
    gemm_body(As, Bs, A, B, bias, C, N, K, blockIdx.y*128, blockIdx.x*128);
}

// fused Q/K/V projections: blockIdx.x 0..15 -> Q cols, 16..19 -> K, 20..23 -> V
__global__ __launch_bounds__(256)
void gemm_qkv(const u16* __restrict__ A,  const u16* __restrict__ Bq,
              const u16* __restrict__ Bk, const u16* __restrict__ Bv,
              float* __restrict__ Cq, float* __restrict__ Ck, float* __restrict__ Cv) {
    __shared__ __align__(16) u16 As[128*32];
    __shared__ __align__(16) u16 Bs[128*32];
    const int bx = blockIdx.x;
    const u16* B; float* C; int N, n0;
    if (bx < 16)      { B = Bq; C = Cq; N = 2048; n0 = bx * 128; }
    else if (bx < 20) { B = Bk; C = Ck; N = 512;  n0 = (bx-16) * 128; }
    else              { B = Bv; C = Cv; N = 512;  n0 = (bx-20) * 128; }
    gemm_body(As, Bs, A, B, nullptr, C, N, 2048, blockIdx.y*128, n0);
}

// ---------------------------------------------------------------------------
// Fused RMSNorm + RoPE for q and k, fp32 in -> bf16 out.
// blocks [0, 16384): q rows; [16384, 20480): k rows. One wave per D=128 row.
// ---------------------------------------------------------------------------
__global__ __launch_bounds__(256)
void rmsnorm_rope_qk(const float* __restrict__ qf, const float* __restrict__ kf,
                     const float* __restrict__ qw, const float* __restrict__ kw,
                     u16* __restrict__ qo, u16* __restrict__ ko) {
    const int blk  = blockIdx.x;
    const int sub  = threadIdx.x >> 6;
    const int lane = threadIdx.x & 63;
    const float* in; const float* w; u16* out; int row, nheads; float scale;
    if (blk < 16384) {
        in = qf; w = qw; out = qo; nheads = NH; scale = 0.08838834764831845f;
        row = blk * 4 + sub;
    } else {
        in = kf; w = kw; out = ko; nheads = NG; scale = 1.0f;
        row = (blk - 16384) * 4 + sub;
    }
    const float* p = in + (size_t)row * 128;
    float x1 = p[lane], x2 = p[lane + 64];
    float ss = x1*x1 + x2*x2;
#pragma unroll
    for (int off = 32; off >= 1; off >>= 1) ss += __shfl_xor(ss, off, 64);
    float inv = 1.0f / (sqrtf(ss * (1.0f/128.0f)) + 1e-6f);
    float x1n = w[lane]      * x1 * inv;
    float x2n = w[lane + 64] * x2 * inv;
    int tpos = (row / nheads) & (T_SEQ - 1);
    float invfreq = powf(10000.0f, -(float)lane / 64.0f);
    float s, c;
    sincosf((float)tpos * invfreq, &s, &c);
    out[(size_t)row*128 + lane]      = f2bf((x1n * c + x2n * s) * scale);
    out[(size_t)row*128 + lane + 64] = f2bf((x2n * c - x1n * s) * scale);
}

// ---------------------------------------------------------------------------
// V cast fp32->bf16 + transpose: v (B,T,G,D) -> vt (B,G,D,T).
// ---------------------------------------------------------------------------
__global__ __launch_bounds__(256)
void v_cast_transpose(const float* __restrict__ v, u16* __restrict__ vt) {
    __shared__ u16 Lt[128 * 66];
    const int t  = threadIdx.x;
    const int t0 = blockIdx.x * 64;
    const int bg = blockIdx.y;
    const int b  = bg / NG, g = bg % NG;
#pragma unroll
    for (int rep = 0; rep < 8; ++rep) {
        int idx = rep * 256 + t;
        int i   = idx >> 5;
        int c   = idx & 31;
        float4 f = *(const float4*)(v + ((size_t)(b*T_SEQ + t0 + i)*NG + g)*DH + c*4);
        Lt[(c*4+0)*66 + i] = f2bf(f.x);
        Lt[(c*4+1)*66 + i] = f2bf(f.y);
        Lt[(c*4+2)*66 + i] = f2bf(f.z);
        Lt[(c*4+3)*66 + i] = f2bf(f.w);
    }
    __syncthreads();
#pragma unroll
    for (int rep = 0; rep < 4; ++rep) {
        int idx = rep * 256 + t;
        int d = idx >> 3, c = idx & 7;
        const u16* src = &Lt[d*66 + c*8];
        uint4 val;
        val.x = *(const unsigned int*)(src + 0);
        val.y = *(const unsigned int*)(src + 2);
        val.z = *(const unsigned int*)(src + 4);
        val.w = *(const unsigned int*)(src + 6);
        *(uint4*)(vt + ((size_t)(bg*DH + d))*T_SEQ + t0 + c*8) = val;
    }
}

// ---------------------------------------------------------------------------
// MFMA flash attention v7: split-K 8-wave blocks.
// Block = 512 thr = 8 waves = 4 heads x 2 key-splits; each wave 32 q-rows.
// Wave (h, s) computes K-tiles kt == s (mod 2) into private partial accO/ls
// (soft-cap bounds scores -> no running max -> partials combine by addition).
// Doubles wave count to 4096 -> 16 waves/CU (v6 was concurrency-starved at
// 4.3 avg waves/CU: short blocks retired early). Per pair-step: stage both
// tiles (slot0 even, slot1 odd) via gll16 DMA w/ pre-swizzled source, one
// vmcnt(0)+barrier; sibling block's waves hide the DMA (m97 pattern).
// P store uses permuted-row layout pi(x)=(x&3)*4+(x>>2) + sigma swizzle
// ((p&3)<<1)|((p>>2)&1): the 4 rows of each b16 store hit 4 distinct bank
// octets -> conflict-free (v6's residual 2.16M conflicts were these stores).
// LDS 80KB = exactly 2 blocks/CU; VGPR must stay <=128 (launch_bounds 512,4).
// ---------------------------------------------------------------------------
__global__ __launch_bounds__(512, 4)
void flash_attn_mfma(const u16* __restrict__ qh, const u16* __restrict__ kh,
                     const u16* __restrict__ vt, u16* __restrict__ y) {
    __shared__ __align__(16) u16 smem[40960];   // 80 KB
    u16* Ks = smem;            // [2][64*128]  swizzled K tiles (even/odd slot)
    u16* Vs = smem + 16384;    // [2][128*64]  swizzled V tiles
    u16* Ps = smem + 32768;    // [128*64]     per-wave 16-row P scratch

    const int t    = threadIdx.x;
    const int lane = t & 63, w = t >> 6;            // w = 0..7
    const int h4   = w & 3,  s = w >> 2;            // head-in-group, key-split
    const int l15  = lane & 15, quad = lane >> 4;
    const int bg   = blockIdx.y;
    const int b    = bg >> 2, g = bg & 3;
    const int chunk = b ? (int)blockIdx.x : (63 - (int)blockIdx.x);
    const int q0   = chunk * 32;
    const int h    = g * (NH / NG) + h4;

    // tanh-poly coefficients pre-multiplied by log2(e)
    const float C0 =  1.4426950408889634f;
    const float C1 = -0.48089834696298777f;
    const float C2 =  0.19235933878519512f;
    const float C3 = -0.07785972536301652f;

    // Q fragments for both 16-row groups (A-operand: row=l15, k=quad*8..)
    bf16x8 aq[2][4];
#pragma unroll
    for (int m = 0; m < 2; ++m) {
        const u16* qp = qh + ((size_t)(b*T_SEQ + q0 + m*16 + l15) * NH + h) * DH;
#pragma unroll
        for (int kc = 0; kc < 4; ++kc)
            aq[m][kc] = __builtin_bit_cast(bf16x8, *(const uint4*)(qp + kc*32 + quad*8));
    }

    f32x4 accO[2][8];
#pragma unroll
    for (int m = 0; m < 2; ++m)
#pragma unroll
        for (int nd = 0; nd < 8; ++nd) accO[m][nd] = (f32x4){0.f, 0.f, 0.f, 0.f};
    float ls[2][4] = {{0.f,0.f,0.f,0.f},{0.f,0.f,0.f,0.f}};

    const u16* kgb = kh + ((size_t)b*T_SEQ*NG + g)*DH;
    const u16* vgb = vt + ((size_t)(b*NG + g)*DH)*T_SEQ;

    // DMA staging roles: dest is LINEAR in t; source carries the XOR swizzle.
    const int krb = t >> 4, kcl = t & 15;   // K: 2 rounds of 32 rows
    const int vdb = t >> 3, vcl = t & 7;    // V: 2 rounds of 64 d-rows

    const int ktiles = q0/64 + 1;
    const int npairs = (ktiles + 1) >> 1;

    for (int p = 0; p < npairs; ++p) {
        // --- stage tile pair: 2p -> slot0, 2p+1 -> slot1 ---
        {
            const int k0e = 2*p*64;
#pragma unroll
            for (int j = 0; j < 2; ++j) {
                const int kr = j*32 + krb;
                gll16(kgb + (size_t)(k0e + kr)*(NG*DH) + ((kcl ^ (kr & 7)) << 3),
                      (char*)Ks + j*8192 + w*1024);
                const int vd = j*64 + vdb;
                gll16(vgb + (size_t)vd*T_SEQ + k0e + ((vcl ^ (vd & 7)) << 3),
                      (char*)Vs + j*8192 + w*1024);
            }
        }
        if (2*p + 1 < ktiles) {
            const int k0o = (2*p + 1)*64;
#pragma unroll
            for (int j = 0; j < 2; ++j) {
                const int kr = j*32 + krb;
                gll16(kgb + (size_t)(k0o + kr)*(NG*DH) + ((kcl ^ (kr & 7)) << 3),
                      (char*)Ks + 16384 + j*8192 + w*1024);
                const int vd = j*64 + vdb;
                gll16(vgb + (size_t)vd*T_SEQ + k0o + ((vcl ^ (vd & 7)) << 3),
                      (char*)Vs + 16384 + j*8192 + w*1024);
            }
        }
        asm volatile("s_waitcnt vmcnt(0)" ::: "memory");
        __syncthreads();

        const int kt = 2*p + s;
        if (kt < ktiles) {
            const u16* Kb = Ks + s*8192;
            const u16* Vb = Vs + s*8192;
            const int k0 = kt * 64;
            const bool diag = (kt == ktiles - 1);

            // --- S = Q K^T : 32 rows x 64 keys, K-fragments shared by groups
            f32x4 accS[2][4];
#pragma unroll
            for (int m = 0; m < 2; ++m)
#pragma unroll
                for (int nt = 0; nt < 4; ++nt) accS[m][nt] = (f32x4){0.f,0.f,0.f,0.f};

            __builtin_amdgcn_s_setprio(1);
#pragma unroll
            for (int nt = 0; nt < 4; ++nt) {
                const int krow = nt*16 + l15;
                const int kswz = (krow & 7) << 3;
#pragma unroll
                for (int kc = 0; kc < 4; ++kc) {
                    bf16x8 bk = __builtin_bit_cast(bf16x8,
                        *(const uint4*)&Kb[krow*128 + ((kc*32 + quad*8) ^ kswz)]);
                    accS[0][nt] = __builtin_amdgcn_mfma_f32_16x16x32_bf16(aq[0][kc], bk, accS[0][nt], 0, 0, 0);
                    accS[1][nt] = __builtin_amdgcn_mfma_f32_16x16x32_bf16(aq[1][kc], bk, accS[1][nt], 0, 0, 0);
                }
            }
            __builtin_amdgcn_s_setprio(0);

            // --- soft-cap + causal(diag only) + exp2; P via swizzled LDS ---
            bf16x8 ap[2][2];
#pragma unroll
            for (int m = 0; m < 2; ++m) {
#pragma unroll
                for (int nt = 0; nt < 4; ++nt) {
                    const int colg = k0 + nt*16 + l15;
#pragma unroll
                    for (int r = 0; r < 4; ++r) {
                        float sv = accS[m][nt][r];
                        float z = sv * 0.02f;         // s/50
                        float u = z * z;
                        float poly = fmaf(u, fmaf(u, fmaf(u, C3, C2), C1), C0);
                        float pv = __builtin_amdgcn_exp2f(sv * poly);
                        if (diag) {
                            const int rowg = q0 + m*16 + quad*4 + r;
                            pv = (colg > rowg) ? 0.f : pv;
                        }
                        ls[m][r] += pv;
                        // permuted row pi(quad*4+r) = r*4+quad; sigma = (quad<<1)|(r&1)
                        const int prow = w*16 + r*4 + quad;
                        const int pswz = ((quad << 1) | (r & 1)) << 3;
                        Ps[prow*64 + ((nt*16 + l15) ^ pswz)] = f2bf(pv);
                    }
                }
                const int srow = (l15 & 3)*4 + (l15 >> 2);
                const int arow = w*16 + srow;
                const int aswz = (((l15 >> 2) << 1) | (l15 & 1)) << 3;
                ap[m][0] = __builtin_bit_cast(bf16x8,
                    *(const uint4*)&Ps[arow*64 + ((quad*8)      ^ aswz)]);
                ap[m][1] = __builtin_bit_cast(bf16x8,
                    *(const uint4*)&Ps[arow*64 + ((32 + quad*8) ^ aswz)]);
            }

            // --- O += P V : V-fragments shared by both row-groups ---
            __builtin_amdgcn_s_setprio(1);
#pragma unroll
            for (int nd = 0; nd < 8; ++nd) {
                const int vrow = nd*16 + l15;
                const int vswz = (vrow & 7) << 3;
#pragma unroll
                for (int kc = 0; kc < 2; ++kc) {
                    bf16x8 bv = __builtin_bit_cast(bf16x8,
                        *(const uint4*)&Vb[vrow*64 + ((kc*32 + quad*8) ^ vswz)]);
                    accO[0][nd] = __builtin_amdgcn_mfma_f32_16x16x32_bf16(ap[0][kc], bv, accO[0][nd], 0, 0, 0);
                    accO[1][nd] = __builtin_amdgcn_mfma_f32_16x16x32_bf16(ap[1][kc], bv, accO[1][nd], 0, 0, 0);
                }
            }
            __builtin_amdgcn_s_setprio(0);
        }
        __syncthreads();
    }

    // --- combine the two key-splits (pure addition; no max bookkeeping) ---
    if (s == 1) {
        float* od = (float*)smem + h4*4096;       // 16KB per head in Ks/Vs area
        float* ld = (float*)smem + 16384 + h4*512; // ls partials in Ps area
#pragma unroll
        for (int m = 0; m < 2; ++m) {
#pragma unroll
            for (int nd = 0; nd < 8; ++nd)
                *(f32x4*)(od + (m*8 + nd)*256 + lane*4) = accO[m][nd];
#pragma unroll
            for (int r = 0; r < 4; ++r)
                ld[(m*4 + r)*64 + lane] = ls[m][r];
        }
    }
    __syncthreads();
    if (s == 0) {
        const float* od = (const float*)smem + h4*4096;
        const float* ld = (const float*)smem + 16384 + h4*512;
#pragma unroll
        for (int m = 0; m < 2; ++m) {
#pragma unroll
            for (int nd = 0; nd < 8; ++nd)
                accO[m][nd] += *(const f32x4*)(od + (m*8 + nd)*256 + lane*4);
#pragma unroll
            for (int r = 0; r < 4; ++r)
                ls[m][r] += ld[(m*4 + r)*64 + lane];
        }

        // --- final row-sum reduction across the 16 l15 lanes, write y ---
#pragma unroll
        for (int m = 0; m < 2; ++m)
#pragma unroll
            for (int r = 0; r < 4; ++r) {
                float v = ls[m][r];
                v += __shfl_xor(v, 1, 64);
                v += __shfl_xor(v, 2, 64);
                v += __shfl_xor(v, 4, 64);
                v += __shfl_xor(v, 8, 64);
                const float invl = 1.f / v;
                u16* yp = y + (size_t)(b*T_SEQ + q0 + m*16 + quad*4 + r) * C_DIM + h*DH;
#pragma unroll
                for (int nd = 0; nd < 8; ++nd)
                    yp[nd*16 + l15] = f2bf(accO[m][nd][r] * invl);
            }
    }
}

// ---------------------------------------------------------------------------
extern "C" void kernel_launch(void* const* d_in, const int* in_sizes, int n_in,
                              void* d_out, int out_size, void* d_ws, size_t ws_size,
                              hipStream_t stream) {
    const float* x  = (const float*)d_in[0];
    const float* Wq = (const float*)d_in[1];
    const float* Wk = (const float*)d_in[2];
    const float* Wv = (const float*)d_in[3];
    const float* Wo = (const float*)d_in[4];
    const float* bo = (const float*)d_in[5];
    const float* qw = (const float*)d_in[6];
    const float* kw = (const float*)d_in[7];
    float* out = (float*)d_out;

    const size_t qE = (size_t)BATCH * T_SEQ * NH * DH;   // 8,388,608
    const size_t kE = (size_t)BATCH * T_SEQ * NG * DH;   // 2,097,152
    const size_t wqE = (size_t)C_DIM * C_DIM;            // 4,194,304

    float* qf  = (float*)d_ws;          // qE floats
    float* kf  = qf + qE;               // kE floats
    float* vf  = kf + kE;               // kE floats
    u16*   qh  = (u16*)(vf + kE);       // qE
    u16*   khb = qh + qE;               // kE
    u16*   vtb = khb + kE;              // kE
    u16*   xh  = vtb + kE;              // qE
    u16*   wqh = xh + qE;               // wqE
    u16*   wkh = wqh + wqE;             // wkE
    u16*   wvh = wkh + (size_t)(NG*DH)*C_DIM;            // wkE
    u16*   woh = (u16*)kf;              // wqE (reuses kf: dead after rmsnorm)
    u16*   yh  = (u16*)qf;              // qE  (reuses qf: dead after rmsnorm)

    const int M = BATCH * T_SEQ;   // 4096
    dim3 blk(256);

    cast_multi<<<dim3(7168), blk, 0, stream>>>(x, Wq, Wk, Wv, xh, wqh, wkh, wvh);

    gemm_qkv<<<dim3(24, M/128), blk, 0, stream>>>(xh, wqh, wkh, wvh, qf, kf, vf);

    rmsnorm_rope_qk<<<dim3(M*NH/4 + M*NG/4), blk, 0, stream>>>(qf, kf, qw, kw, qh, khb);
    v_cast_transpose<<<dim3(T_SEQ/64, BATCH*NG), blk, 0, stream>>>(vf, vtb);

    cast_f32_bf16<<<dim3(wqE/8/256), blk, 0, stream>>>(Wo, woh, wqE/8);

    flash_attn_mfma<<<dim3(T_SEQ/32, BATCH*NG), dim3(512), 0, stream>>>(qh, khb, vtb, yh);

    gemm_nt_bf16<<<dim3(C_DIM/128, M/128), blk, 0, stream>>>(yh, woh, bo, out, C_DIM, C_DIM);
}

// Round 3
// 343.814 us; speedup vs baseline: 1.4007x; 1.4007x over previous
//
#include <hip/hip_runtime.h>
#include <math.h>

#define T_SEQ 2048
#define C_DIM 2048
#define NH    16
#define NG    4
#define DH    128
#define BATCH 2

typedef unsigned short u16;
typedef __bf16 bf16_t;
typedef bf16_t bf16x8 __attribute__((ext_vector_type(8)));
typedef float  f32x4  __attribute__((ext_vector_type(4)));

static __device__ __forceinline__ u16 f2bf(float f) {
    return __builtin_bit_cast(u16, (__bf16)f);
}

// async global->LDS, 16B per lane. lds must be wave-uniform base; HW adds lane*16.
static __device__ __forceinline__ void gll16(const void* g, void* lds) {
    __builtin_amdgcn_global_load_lds(
        (const __attribute__((address_space(1))) void*)(unsigned long long)(g),
        (__attribute__((address_space(3))) void*)(unsigned int)(unsigned long long)(lds),
        16, 0, 0);
}

// ---------------------------------------------------------------------------
// fused fp32->bf16 cast for x, Wq, Wk, Wv (8 elems/thread, flat if-chain)
// chunk counts: x 1048576 | Wq 524288 | Wk 131072 | Wv 131072  (sum = 7168*256)
// ---------------------------------------------------------------------------
__global__ __launch_bounds__(256)
void cast_multi(const float* __restrict__ x,  const float* __restrict__ wq,
                const float* __restrict__ wk, const float* __restrict__ wv,
                u16* __restrict__ xo, u16* __restrict__ wqo,
                u16* __restrict__ wko, u16* __restrict__ wvo) {
    int i = blockIdx.x * 256 + threadIdx.x;
    const float* src; u16* dst; int off;
    if (i < 1048576)      { src = x;  dst = xo;  off = i; }
    else if (i < 1572864) { src = wq; dst = wqo; off = i - 1048576; }
    else if (i < 1703936) { src = wk; dst = wko; off = i - 1572864; }
    else                  { src = wv; dst = wvo; off = i - 1703936; }
    const float4* p = (const float4*)src + (size_t)off * 2;
    float4 a = p[0], b = p[1];
    u16 u[8] = {f2bf(a.x), f2bf(a.y), f2bf(a.z), f2bf(a.w),
                f2bf(b.x), f2bf(b.y), f2bf(b.z), f2bf(b.w)};
    *(uint4*)(dst + (size_t)off * 8) = *(const uint4*)u;
}

__global__ __launch_bounds__(256)
void cast_f32_bf16(const float* __restrict__ in, u16* __restrict__ out, int n8) {
    int i = blockIdx.x * 256 + threadIdx.x;
    if (i >= n8) return;
    const float4* p = (const float4*)in + (size_t)i * 2;
    float4 a = p[0], b = p[1];
    u16 u[8] = {f2bf(a.x), f2bf(a.y), f2bf(a.z), f2bf(a.w),
                f2bf(b.x), f2bf(b.y), f2bf(b.z), f2bf(b.w)};
    *(uint4*)(out + (size_t)i * 8) = *(const uint4*)u;
}

// ---------------------------------------------------------------------------
// rotary tables: cos/sin(t * 10000^(-l/64)) for t in [0,2048), l in [0,64).
// Input-independent; computed once (131K transcendentals vs 5.24M when done
// per-row inside rmsnorm). 1 MB total -> L2/L3-resident for the consumer.
// ---------------------------------------------------------------------------
__global__ __launch_bounds__(256)
void rope_tables(float* __restrict__ cosT, float* __restrict__ sinT) {
    int i = blockIdx.x * 256 + threadIdx.x;     // 131072 entries
    int tp = i >> 6, ln = i & 63;
    // 10000^(-ln/64) = exp2(-ln * log2(10000)/64)
    float invfreq = __builtin_amdgcn_exp2f(-(float)ln * (13.287712379549449f / 64.0f));
    float s, c;
    sincosf((float)tp * invfreq, &s, &c);
    cosT[i] = c;
    sinT[i] = s;
}

// ---------------------------------------------------------------------------
// C(fp32, M x N) = A_bf16(M,K) @ B_bf16(N,K)^T (+bias)
// 128x128 tile, BK=32, 4 waves, each wave 64x64 (4x4 MFMA 16x16x32).
// ---------------------------------------------------------------------------
static __device__ __forceinline__ void gemm_body(
        u16* As, u16* Bs,
        const u16* __restrict__ A, const u16* __restrict__ B,
        const float* __restrict__ bias, float* __restrict__ C,
        int N, int K, int m0, int n0) {
    const int t    = threadIdx.x;
    const int lane = t & 63, w = t >> 6;
    const int l15  = lane & 15, quad = lane >> 4;
    const int wr   = w >> 1, wc = w & 1;

    f32x4 acc[4][4];
#pragma unroll
    for (int mt = 0; mt < 4; ++mt)
#pragma unroll
        for (int nt = 0; nt < 4; ++nt) acc[mt][nt] = (f32x4){0.f, 0.f, 0.f, 0.f};

    const int off0 = w*2048 + lane*16;
    const int r0 = off0 >> 6,          c0 = (off0 & 63) >> 1;
    const int r1 = (off0+1024) >> 6,   c1 = ((off0+1024) & 63) >> 1;
    const u16* Ag0 = A + (size_t)(m0 + r0) * K + c0;
    const u16* Ag1 = A + (size_t)(m0 + r1) * K + c1;
    const u16* Bg0 = B + (size_t)(n0 + r0) * K + c0;
    const u16* Bg1 = B + (size_t)(n0 + r1) * K + c1;
    char* AsB = (char*)As; char* BsB = (char*)Bs;
    const int ldsOff0 = w*2048, ldsOff1 = w*2048 + 1024;

    for (int k0 = 0; k0 < K; k0 += 32) {
        gll16(Ag0 + k0, AsB + ldsOff0);
        gll16(Ag1 + k0, AsB + ldsOff1);
        gll16(Bg0 + k0, BsB + ldsOff0);
        gll16(Bg1 + k0, BsB + ldsOff1);
        __syncthreads();
        bf16x8 af[4], bf[4];
#pragma unroll
        for (int mt = 0; mt < 4; ++mt)
            af[mt] = __builtin_bit_cast(bf16x8,
                *(const uint4*)&As[(wr*64 + mt*16 + l15)*32 + quad*8]);
#pragma unroll
        for (int nt = 0; nt < 4; ++nt)
            bf[nt] = __builtin_bit_cast(bf16x8,
                *(const uint4*)&Bs[(wc*64 + nt*16 + l15)*32 + quad*8]);
#pragma unroll
        for (int mt = 0; mt < 4; ++mt)
#pragma unroll
            for (int nt = 0; nt < 4; ++nt)
                acc[mt][nt] = __builtin_amdgcn_mfma_f32_16x16x32_bf16(
                                  af[mt], bf[nt], acc[mt][nt], 0, 0, 0);
        __syncthreads();
    }

#pragma unroll
    for (int mt = 0; mt < 4; ++mt)
#pragma unroll
        for (int nt = 0; nt < 4; ++nt) {
            const int col = n0 + wc*64 + nt*16 + l15;
            const float bv = bias ? bias[col] : 0.f;
#pragma unroll
            for (int r = 0; r < 4; ++r) {
                const int row = m0 + wr*64 + mt*16 + quad*4 + r;
                C[(size_t)row * N + col] = acc[mt][nt][r] + bv;
            }
        }
}

__global__ __launch_bounds__(256)
void gemm_nt_bf16(const u16* __restrict__ A, const u16* __restrict__ B,
                  const float* __restrict__ bias, float* __restrict__ C,
                  int N, int K) {
    __shared__ __align__(16) u16 As[128*32];
    __shared__ __align__(16) u16 Bs[128*32];
    gemm_body(As, Bs, A, B, bias, C, N, K, blockIdx.y*128, blockIdx.x*128);
}

// fused Q/K/V projections: blockIdx.x 0..15 -> Q cols, 16..19 -> K, 20..23 -> V
__global__ __launch_bounds__(256)
void gemm_qkv(const u16* __restrict__ A,  const u16* __restrict__ Bq,
              const u16* __restrict__ Bk, const u16* __restrict__ Bv,
              float* __restrict__ Cq, float* __restrict__ Ck, float* __restrict__ Cv) {
    __shared__ __align__(16) u16 As[128*32];
    __shared__ __align__(16) u16 Bs[128*32];
    const int bx = blockIdx.x;
    const u16* B; float* C; int N, n0;
    if (bx < 16)      { B = Bq; C = Cq; N = 2048; n0 = bx * 128; }
    else if (bx < 20) { B = Bk; C = Ck; N = 512;  n0 = (bx-16) * 128; }
    else              { B = Bv; C = Cv; N = 512;  n0 = (bx-20) * 128; }
    gemm_body(As, Bs, A, B, nullptr, C, N, 2048, blockIdx.y*128, n0);
}

// ---------------------------------------------------------------------------
// Fused RMSNorm + RoPE for q and k, fp32 in -> bf16 out.
// blocks [0, 16384): q rows; [16384, 20480): k rows. One wave per D=128 row.
// cos/sin from precomputed tables (L2-resident) instead of powf+sincosf.
// ---------------------------------------------------------------------------
__global__ __launch_bounds__(256)
void rmsnorm_rope_qk(const float* __restrict__ qf, const float* __restrict__ kf,
                     const float* __restrict__ qw, const float* __restrict__ kw,
                     const float* __restrict__ cosT, const float* __restrict__ sinT,
                     u16* __restrict__ qo, u16* __restrict__ ko) {
    const int blk  = blockIdx.x;
    const int sub  = threadIdx.x >> 6;
    const int lane = threadIdx.x & 63;
    const float* in; const float* w; u16* out; int row, nheads; float scale;
    if (blk < 16384) {
        in = qf; w = qw; out = qo; nheads = NH; scale = 0.08838834764831845f;
        row = blk * 4 + sub;
    } else {
        in = kf; w = kw; out = ko; nheads = NG; scale = 1.0f;
        row = (blk - 16384) * 4 + sub;
    }
    const float* p = in + (size_t)row * 128;
    float x1 = p[lane], x2 = p[lane + 64];
    float ss = x1*x1 + x2*x2;
#pragma unroll
    for (int off = 32; off >= 1; off >>= 1) ss += __shfl_xor(ss, off, 64);
    float inv = 1.0f / (sqrtf(ss * (1.0f/128.0f)) + 1e-6f);
    float x1n = w[lane]      * x1 * inv;
    float x2n = w[lane + 64] * x2 * inv;
    int tpos = (row / nheads) & (T_SEQ - 1);
    float c = cosT[tpos*64 + lane];
    float s = sinT[tpos*64 + lane];
    out[(size_t)row*128 + lane]      = f2bf((x1n * c + x2n * s) * scale);
    out[(size_t)row*128 + lane + 64] = f2bf((x2n * c - x1n * s) * scale);
}

// ---------------------------------------------------------------------------
// V cast fp32->bf16 + transpose: v (B,T,G,D) -> vt (B,G,D,T).
// ---------------------------------------------------------------------------
__global__ __launch_bounds__(256)
void v_cast_transpose(const float* __restrict__ v, u16* __restrict__ vt) {
    __shared__ u16 Lt[128 * 66];
    const int t  = threadIdx.x;
    const int t0 = blockIdx.x * 64;
    const int bg = blockIdx.y;
    const int b  = bg / NG, g = bg % NG;
#pragma unroll
    for (int rep = 0; rep < 8; ++rep) {
        int idx = rep * 256 + t;
        int i   = idx >> 5;
        int c   = idx & 31;
        float4 f = *(const float4*)(v + ((size_t)(b*T_SEQ + t0 + i)*NG + g)*DH + c*4);
        Lt[(c*4+0)*66 + i] = f2bf(f.x);
        Lt[(c*4+1)*66 + i] = f2bf(f.y);
        Lt[(c*4+2)*66 + i] = f2bf(f.z);
        Lt[(c*4+3)*66 + i] = f2bf(f.w);
    }
    __syncthreads();
#pragma unroll
    for (int rep = 0; rep < 4; ++rep) {
        int idx = rep * 256 + t;
        int d = idx >> 3, c = idx & 7;
        const u16* src = &Lt[d*66 + c*8];
        uint4 val;
        val.x = *(const unsigned int*)(src + 0);
        val.y = *(const unsigned int*)(src + 2);
        val.z = *(const unsigned int*)(src + 4);
        val.w = *(const unsigned int*)(src + 6);
        *(uint4*)(vt + ((size_t)(bg*DH + d))*T_SEQ + t0 + c*8) = val;
    }
}

// ---------------------------------------------------------------------------
// MFMA flash attention v8 = v6 structure (verified 80us, no spill) + the
// register-neutral micro-opts correctness-proven by the v7 run:
//   - folded log2(e) into tanh-poly coefficients
//   - causal mask only on the diagonal tile (wave-uniform skip elsewhere)
//   - permuted conflict-free P store layout (pi(x)=(x&3)*4+(x>>2))
//   - s_setprio(1) around both MFMA nests (T5: +4-7% on attn, m191)
// Plus XCD-affinity grid: flat 512 blocks, bg = bid & 7 -> each XCD's L2
// holds exactly one (b,g)'s K/V (1MB << 4MB, was 8MB across all bgs).
// v7 POST-MORTEM: 8-wave split-K spilled accumulators (WRITE_SIZE 16->338MB,
// VGPR 64) -> never raise per-block wave count with this register footprint.
// ---------------------------------------------------------------------------
__global__ __launch_bounds__(256, 2)
void flash_attn_mfma(const u16* __restrict__ qh, const u16* __restrict__ kh,
                     const u16* __restrict__ vt, u16* __restrict__ y) {
    __shared__ __align__(16) u16 Ks[2][64*128];   // [buf][key][d]   swizzled
    __shared__ __align__(16) u16 Vs[2][128*64];   // [buf][d][key]   swizzled
    __shared__ __align__(16) u16 Ps[64*64];       // [4 waves x 16 rows][key]

    const int t    = threadIdx.x;
    const int lane = t & 63, w = t >> 6;            // w = 0..3 = head-in-group
    const int l15  = lane & 15, quad = lane >> 4;
    const int bid  = blockIdx.x;
    const int bg   = bid & 7;                       // bg == XCD id (L2 affinity)
    const int b    = bg >> 2, g = bg & 3;
    const int cidx = bid >> 3;                      // 0..63
    const int chunk = b ? cidx : (63 - cidx);       // pairing balances load
    const int q0   = chunk * 32;
    const int h    = g * (NH / NG) + w;

    // tanh-poly coefficients pre-multiplied by log2(e)
    const float C0 =  1.4426950408889634f;
    const float C1 = -0.48089834696298777f;
    const float C2 =  0.19235933878519512f;
    const float C3 = -0.07785972536301652f;

    // Q fragments for both 16-row groups (A-operand: row=l15, k=quad*8..)
    bf16x8 aq[2][4];
#pragma unroll
    for (int m = 0; m < 2; ++m) {
        const u16* qp = qh + ((size_t)(b*T_SEQ + q0 + m*16 + l15) * NH + h) * DH;
#pragma unroll
        for (int kc = 0; kc < 4; ++kc)
            aq[m][kc] = __builtin_bit_cast(bf16x8, *(const uint4*)(qp + kc*32 + quad*8));
    }

    f32x4 accO[2][8];
#pragma unroll
    for (int m = 0; m < 2; ++m)
#pragma unroll
        for (int nd = 0; nd < 8; ++nd) accO[m][nd] = (f32x4){0.f, 0.f, 0.f, 0.f};
    float ls[2][4] = {{0.f,0.f,0.f,0.f},{0.f,0.f,0.f,0.f}};

    const u16* kgb = kh + ((size_t)b*T_SEQ*NG + g)*DH;
    const u16* vgb = vt + ((size_t)(b*NG + g)*DH)*T_SEQ;

    // DMA staging roles (per thread, 4 passes each for K and V):
    // dest is LINEAR (wave-uniform base + lane*16); source carries the swizzle.
    const int krb = t >> 4, kcl = t & 15;
    const int vdb = t >> 3, vcl = t & 7;

    const int ktiles = q0/64 + 1;

    // prologue: stage tile 0 -> buf 0
#pragma unroll
    for (int j = 0; j < 4; ++j) {
        const int kr = j*16 + krb;
        gll16(kgb + (size_t)kr*(NG*DH) + ((kcl ^ (kr & 7)) << 3),
              (char*)Ks[0] + j*4096 + w*1024);
        const int vd = j*32 + vdb;
        gll16(vgb + (size_t)vd*T_SEQ + ((vcl ^ (vd & 7)) << 3),
              (char*)Vs[0] + j*4096 + w*1024);
    }

    for (int kt = 0; kt < ktiles; ++kt) {
        // syncthreads drains vmcnt(0): buf[kt&1] staged by ALL waves & visible;
        // also fences buf[(kt+1)&1] reads (iter kt-1) from the stage below.
        asm volatile("s_waitcnt vmcnt(0)" ::: "memory");
        __syncthreads();

        if (kt + 1 < ktiles) {          // issue next-tile DMA, overlaps compute
            const int k0n = (kt + 1) * 64, bn = (kt + 1) & 1;
#pragma unroll
            for (int j = 0; j < 4; ++j) {
                const int kr = j*16 + krb;
                gll16(kgb + (size_t)(k0n + kr)*(NG*DH) + ((kcl ^ (kr & 7)) << 3),
                      (char*)Ks[bn] + j*4096 + w*1024);
                const int vd = j*32 + vdb;
                gll16(vgb + (size_t)vd*T_SEQ + k0n + ((vcl ^ (vd & 7)) << 3),
                      (char*)Vs[bn] + j*4096 + w*1024);
            }
        }

        const u16* Kb = Ks[kt & 1];
        const u16* Vb = Vs[kt & 1];
        const int k0 = kt * 64;
        const bool diag = (kt == ktiles - 1);

        // --- S = Q K^T : 32 rows x 64 keys, K-fragments shared by both groups
        f32x4 accS[2][4];
#pragma unroll
        for (int m = 0; m < 2; ++m)
#pragma unroll
            for (int nt = 0; nt < 4; ++nt) accS[m][nt] = (f32x4){0.f,0.f,0.f,0.f};

        __builtin_amdgcn_s_setprio(1);
#pragma unroll
        for (int nt = 0; nt < 4; ++nt) {
            const int krow = nt*16 + l15;
            const int kswz = (krow & 7) << 3;
#pragma unroll
            for (int kc = 0; kc < 4; ++kc) {
                bf16x8 bk = __builtin_bit_cast(bf16x8,
                    *(const uint4*)&Kb[krow*128 + ((kc*32 + quad*8) ^ kswz)]);
                accS[0][nt] = __builtin_amdgcn_mfma_f32_16x16x32_bf16(aq[0][kc], bk, accS[0][nt], 0, 0, 0);
                accS[1][nt] = __builtin_amdgcn_mfma_f32_16x16x32_bf16(aq[1][kc], bk, accS[1][nt], 0, 0, 0);
            }
        }
        __builtin_amdgcn_s_setprio(0);

        // --- soft-cap + causal(diag only) + exp2; P via permuted LDS layout ---
        bf16x8 ap[2][2];
#pragma unroll
        for (int m = 0; m < 2; ++m) {
#pragma unroll
            for (int nt = 0; nt < 4; ++nt) {
                const int colg = k0 + nt*16 + l15;
#pragma unroll
                for (int r = 0; r < 4; ++r) {
                    float sv = accS[m][nt][r];
                    float z = sv * 0.02f;         // s/50
                    float u = z * z;
                    float poly = fmaf(u, fmaf(u, fmaf(u, C3, C2), C1), C0);
                    float pv = __builtin_amdgcn_exp2f(sv * poly);
                    if (diag) {
                        const int rowg = q0 + m*16 + quad*4 + r;
                        pv = (colg > rowg) ? 0.f : pv;
                    }
                    ls[m][r] += pv;
                    // permuted row pi(quad*4+r) = r*4+quad; sigma = (quad<<1)|(r&1)
                    const int prow = w*16 + r*4 + quad;
                    const int pswz = ((quad << 1) | (r & 1)) << 3;
                    Ps[prow*64 + ((nt*16 + l15) ^ pswz)] = f2bf(pv);
                }
            }
            const int srow = (l15 & 3)*4 + (l15 >> 2);
            const int arow = w*16 + srow;
            const int aswz = (((l15 >> 2) << 1) | (l15 & 1)) << 3;
            ap[m][0] = __builtin_bit_cast(bf16x8,
                *(const uint4*)&Ps[arow*64 + ((quad*8)      ^ aswz)]);
            ap[m][1] = __builtin_bit_cast(bf16x8,
                *(const uint4*)&Ps[arow*64 + ((32 + quad*8) ^ aswz)]);
        }

        // --- O += P V : V-fragments shared by both row-groups ---
        __builtin_amdgcn_s_setprio(1);
#pragma unroll
        for (int nd = 0; nd < 8; ++nd) {
            const int vrow = nd*16 + l15;
            const int vswz = (vrow & 7) << 3;
#pragma unroll
            for (int kc = 0; kc < 2; ++kc) {
                bf16x8 bv = __builtin_bit_cast(bf16x8,
                    *(const uint4*)&Vb[vrow*64 + ((kc*32 + quad*8) ^ vswz)]);
                accO[0][nd] = __builtin_amdgcn_mfma_f32_16x16x32_bf16(ap[0][kc], bv, accO[0][nd], 0, 0, 0);
                accO[1][nd] = __builtin_amdgcn_mfma_f32_16x16x32_bf16(ap[1][kc], bv, accO[1][nd], 0, 0, 0);
            }
        }
        __builtin_amdgcn_s_setprio(0);
    }

    // --- final row-sum reduction across the 16 l15 lanes, write y ---
#pragma unroll
    for (int m = 0; m < 2; ++m)
#pragma unroll
        for (int r = 0; r < 4; ++r) {
            float v = ls[m][r];
            v += __shfl_xor(v, 1, 64);
            v += __shfl_xor(v, 2, 64);
            v += __shfl_xor(v, 4, 64);
            v += __shfl_xor(v, 8, 64);
            const float invl = 1.f / v;
            u16* yp = y + (size_t)(b*T_SEQ + q0 + m*16 + quad*4 + r) * C_DIM + h*DH;
#pragma unroll
            for (int nd = 0; nd < 8; ++nd)
                yp[nd*16 + l15] = f2bf(accO[m][nd][r] * invl);
        }
}

// ---------------------------------------------------------------------------
extern "C" void kernel_launch(void* const* d_in, const int* in_sizes, int n_in,
                              void* d_out, int out_size, void* d_ws, size_t ws_size,
                              hipStream_t stream) {
    const float* x  = (const float*)d_in[0];
    const float* Wq = (const float*)d_in[1];
    const float* Wk = (const float*)d_in[2];
    const float* Wv = (const float*)d_in[3];
    const float* Wo = (const float*)d_in[4];
    const float* bo = (const float*)d_in[5];
    const float* qw = (const float*)d_in[6];
    const float* kw = (const float*)d_in[7];
    float* out = (float*)d_out;

    const size_t qE = (size_t)BATCH * T_SEQ * NH * DH;   // 8,388,608
    const size_t kE = (size_t)BATCH * T_SEQ * NG * DH;   // 2,097,152
    const size_t wqE = (size_t)C_DIM * C_DIM;            // 4,194,304
    const size_t wkE = (size_t)(NG*DH) * C_DIM;          // 1,048,576

    float* qf  = (float*)d_ws;          // qE floats
    float* kf  = qf + qE;               // kE floats
    float* vf  = kf + kE;               // kE floats
    u16*   qh  = (u16*)(vf + kE);       // qE
    u16*   khb = qh + qE;               // kE
    u16*   vtb = khb + kE;              // kE
    u16*   xh  = vtb + kE;              // qE
    u16*   wqh = xh + qE;               // wqE
    u16*   wkh = wqh + wqE;             // wkE
    u16*   wvh = wkh + wkE;             // wkE
    float* cosT = (float*)(wvh + wkE);  // 131072 floats
    float* sinT = cosT + 131072;        // 131072 floats
    u16*   woh = (u16*)kf;              // wqE (reuses kf: dead after rmsnorm)
    u16*   yh  = (u16*)qf;              // qE  (reuses qf: dead after rmsnorm)

    const int M = BATCH * T_SEQ;   // 4096
    dim3 blk(256);

    rope_tables<<<dim3(512), blk, 0, stream>>>(cosT, sinT);

    cast_multi<<<dim3(7168), blk, 0, stream>>>(x, Wq, Wk, Wv, xh, wqh, wkh, wvh);

    gemm_qkv<<<dim3(24, M/128), blk, 0, stream>>>(xh, wqh, wkh, wvh, qf, kf, vf);

    rmsnorm_rope_qk<<<dim3(M*NH/4 + M*NG/4), blk, 0, stream>>>(qf, kf, qw, kw, cosT, sinT, qh, khb);
    v_cast_transpose<<<dim3(T_SEQ/64, BATCH*NG), blk, 0, stream>>>(vf, vtb);

    cast_f32_bf16<<<dim3(wqE/8/256), blk, 0, stream>>>(Wo, woh, wqE/8);

    flash_attn_mfma<<<dim3(512), blk, 0, stream>>>(qh, khb, vtb, yh);

    gemm_nt_bf16<<<dim3(C_DIM/128, M/128), blk, 0, stream>>>(yh, woh, bo, out, C_DIM, C_DIM);
}

// Round 6
// 320.761 us; speedup vs baseline: 1.5014x; 1.0719x over previous
//
#include <hip/hip_runtime.h>
#include <math.h>

#define T_SEQ 2048
#define C_DIM 2048
#define NH    16
#define NG    4
#define DH    128
#define BATCH 2

typedef unsigned short u16;
typedef __bf16 bf16_t;
typedef bf16_t bf16x8 __attribute__((ext_vector_type(8)));
typedef float  f32x4  __attribute__((ext_vector_type(4)));

static __device__ __forceinline__ u16 f2bf(float f) {
    return __builtin_bit_cast(u16, (__bf16)f);
}

// async global->LDS, 16B per lane. lds must be wave-uniform base; HW adds lane*16.
static __device__ __forceinline__ void gll16(const void* g, void* lds) {
    __builtin_amdgcn_global_load_lds(
        (const __attribute__((address_space(1))) void*)(unsigned long long)(g),
        (__attribute__((address_space(3))) void*)(unsigned int)(unsigned long long)(lds),
        16, 0, 0);
}

// ---------------------------------------------------------------------------
// fused fp32->bf16 cast for x, Wq, Wk, Wv (8 elems/thread, flat if-chain)
// chunk counts: x 1048576 | Wq 524288 | Wk 131072 | Wv 131072  (sum = 7168*256)
// ---------------------------------------------------------------------------
__global__ __launch_bounds__(256)
void cast_multi(const float* __restrict__ x,  const float* __restrict__ wq,
                const float* __restrict__ wk, const float* __restrict__ wv,
                u16* __restrict__ xo, u16* __restrict__ wqo,
                u16* __restrict__ wko, u16* __restrict__ wvo) {
    int i = blockIdx.x * 256 + threadIdx.x;
    const float* src; u16* dst; int off;
    if (i < 1048576)      { src = x;  dst = xo;  off = i; }
    else if (i < 1572864) { src = wq; dst = wqo; off = i - 1048576; }
    else if (i < 1703936) { src = wk; dst = wko; off = i - 1572864; }
    else                  { src = wv; dst = wvo; off = i - 1703936; }
    const float4* p = (const float4*)src + (size_t)off * 2;
    float4 a = p[0], b = p[1];
    u16 u[8] = {f2bf(a.x), f2bf(a.y), f2bf(a.z), f2bf(a.w),
                f2bf(b.x), f2bf(b.y), f2bf(b.z), f2bf(b.w)};
    *(uint4*)(dst + (size_t)off * 8) = *(const uint4*)u;
}

__global__ __launch_bounds__(256)
void cast_f32_bf16(const float* __restrict__ in, u16* __restrict__ out, int n8) {
    int i = blockIdx.x * 256 + threadIdx.x;
    if (i >= n8) return;
    const float4* p = (const float4*)in + (size_t)i * 2;
    float4 a = p[0], b = p[1];
    u16 u[8] = {f2bf(a.x), f2bf(a.y), f2bf(a.z), f2bf(a.w),
                f2bf(b.x), f2bf(b.y), f2bf(b.z), f2bf(b.w)};
    *(uint4*)(out + (size_t)i * 8) = *(const uint4*)u;
}

// ---------------------------------------------------------------------------
// rotary tables: cos/sin(t * 10000^(-l/64)) for t in [0,2048), l in [0,64).
// ---------------------------------------------------------------------------
__global__ __launch_bounds__(256)
void rope_tables(float* __restrict__ cosT, float* __restrict__ sinT) {
    int i = blockIdx.x * 256 + threadIdx.x;     // 131072 entries
    int tp = i >> 6, ln = i & 63;
    float invfreq = __builtin_amdgcn_exp2f(-(float)ln * (13.287712379549449f / 64.0f));
    float s, c;
    sincosf((float)tp * invfreq, &s, &c);
    cosT[i] = c;
    sinT[i] = s;
}

// ---------------------------------------------------------------------------
// C(fp32, M x N) = A_bf16(M,K) @ B_bf16(N,K)^T (+bias)
// 128x128 tile, BK=32, 4 waves, each wave 64x64 (4x4 MFMA 16x16x32).
// ---------------------------------------------------------------------------
static __device__ __forceinline__ void gemm_body(
        u16* As, u16* Bs,
        const u16* __restrict__ A, const u16* __restrict__ B,
        const float* __restrict__ bias, float* __restrict__ C,
        int N, int K, int m0, int n0) {
    const int t    = threadIdx.x;
    const int lane = t & 63, w = t >> 6;
    const int l15  = lane & 15, quad = lane >> 4;
    const int wr   = w >> 1, wc = w & 1;

    f32x4 acc[4][4];
#pragma unroll
    for (int mt = 0; mt < 4; ++mt)
#pragma unroll
        for (int nt = 0; nt < 4; ++nt) acc[mt][nt] = (f32x4){0.f, 0.f, 0.f, 0.f};

    const int off0 = w*2048 + lane*16;
    const int r0 = off0 >> 6,          c0 = (off0 & 63) >> 1;
    const int r1 = (off0+1024) >> 6,   c1 = ((off0+1024) & 63) >> 1;
    const u16* Ag0 = A + (size_t)(m0 + r0) * K + c0;
    const u16* Ag1 = A + (size_t)(m0 + r1) * K + c1;
    const u16* Bg0 = B + (size_t)(n0 + r0) * K + c0;
    const u16* Bg1 = B + (size_t)(n0 + r1) * K + c1;
    char* AsB = (char*)As; char* BsB = (char*)Bs;
    const int ldsOff0 = w*2048, ldsOff1 = w*2048 + 1024;

    for (int k0 = 0; k0 < K; k0 += 32) {
        gll16(Ag0 + k0, AsB + ldsOff0);
        gll16(Ag1 + k0, AsB + ldsOff1);
        gll16(Bg0 + k0, BsB + ldsOff0);
        gll16(Bg1 + k0, BsB + ldsOff1);
        __syncthreads();
        bf16x8 af[4], bf[4];
#pragma unroll
        for (int mt = 0; mt < 4; ++mt)
            af[mt] = __builtin_bit_cast(bf16x8,
                *(const uint4*)&As[(wr*64 + mt*16 + l15)*32 + quad*8]);
#pragma unroll
        for (int nt = 0; nt < 4; ++nt)
            bf[nt] = __builtin_bit_cast(bf16x8,
                *(const uint4*)&Bs[(wc*64 + nt*16 + l15)*32 + quad*8]);
#pragma unroll
        for (int mt = 0; mt < 4; ++mt)
#pragma unroll
            for (int nt = 0; nt < 4; ++nt)
                acc[mt][nt] = __builtin_amdgcn_mfma_f32_16x16x32_bf16(
                                  af[mt], bf[nt], acc[mt][nt], 0, 0, 0);
        __syncthreads();
    }

#pragma unroll
    for (int mt = 0; mt < 4; ++mt)
#pragma unroll
        for (int nt = 0; nt < 4; ++nt) {
            const int col = n0 + wc*64 + nt*16 + l15;
            const float bv = bias ? bias[col] : 0.f;
#pragma unroll
            for (int r = 0; r < 4; ++r) {
                const int row = m0 + wr*64 + mt*16 + quad*4 + r;
                C[(size_t)row * N + col] = acc[mt][nt][r] + bv;
            }
        }
}

__global__ __launch_bounds__(256)
void gemm_nt_bf16(const u16* __restrict__ A, const u16* __restrict__ B,
                  const float* __restrict__ bias, float* __restrict__ C,
                  int N, int K) {
    __shared__ __align__(16) u16 As[128*32];
    __shared__ __align__(16) u16 Bs[128*32];
    gemm_body(As, Bs, A, B, bias, C, N, K, blockIdx.y*128, blockIdx.x*128);
}

// fused Q/K/V projections: blockIdx.x 0..15 -> Q cols, 16..19 -> K, 20..23 -> V
__global__ __launch_bounds__(256)
void gemm_qkv(const u16* __restrict__ A,  const u16* __restrict__ Bq,
              const u16* __restrict__ Bk, const u16* __restrict__ Bv,
              float* __restrict__ Cq, float* __restrict__ Ck, float* __restrict__ Cv) {
    __shared__ __align__(16) u16 As[128*32];
    __shared__ __align__(16) u16 Bs[128*32];
    const int bx = blockIdx.x;
    const u16* B; float* C; int N, n0;
    if (bx < 16)      { B = Bq; C = Cq; N = 2048; n0 = bx * 128; }
    else if (bx < 20) { B = Bk; C = Ck; N = 512;  n0 = (bx-16) * 128; }
    else              { B = Bv; C = Cv; N = 512;  n0 = (bx-20) * 128; }
    gemm_body(As, Bs, A, B, nullptr, C, N, 2048, blockIdx.y*128, n0);
}

// ---------------------------------------------------------------------------
// Fused RMSNorm + RoPE for q and k, fp32 in -> bf16 out.
// blocks [0, 16384): q rows; [16384, 20480): k rows. One wave per D=128 row.
// cos/sin from precomputed tables (L2-resident) instead of powf+sincosf.
// ---------------------------------------------------------------------------
__global__ __launch_bounds__(256)
void rmsnorm_rope_qk(const float* __restrict__ qf, const float* __restrict__ kf,
                     const float* __restrict__ qw, const float* __restrict__ kw,
                     const float* __restrict__ cosT, const float* __restrict__ sinT,
                     u16* __restrict__ qo, u16* __restrict__ ko) {
    const int blk  = blockIdx.x;
    const int sub  = threadIdx.x >> 6;
    const int lane = threadIdx.x & 63;
    const float* in; const float* w; u16* out; int row, nheads; float scale;
    if (blk < 16384) {
        in = qf; w = qw; out = qo; nheads = NH; scale = 0.08838834764831845f;
        row = blk * 4 + sub;
    } else {
        in = kf; w = kw; out = ko; nheads = NG; scale = 1.0f;
        row = (blk - 16384) * 4 + sub;
    }
    const float* p = in + (size_t)row * 128;
    float x1 = p[lane], x2 = p[lane + 64];
    float ss = x1*x1 + x2*x2;
#pragma unroll
    for (int off = 32; off >= 1; off >>= 1) ss += __shfl_xor(ss, off, 64);
    float inv = 1.0f / (sqrtf(ss * (1.0f/128.0f)) + 1e-6f);
    float x1n = w[lane]      * x1 * inv;
    float x2n = w[lane + 64] * x2 * inv;
    int tpos = (row / nheads) & (T_SEQ - 1);
    float c = cosT[tpos*64 + lane];
    float s = sinT[tpos*64 + lane];
    out[(size_t)row*128 + lane]      = f2bf((x1n * c + x2n * s) * scale);
    out[(size_t)row*128 + lane + 64] = f2bf((x2n * c - x1n * s) * scale);
}

// ---------------------------------------------------------------------------
// V cast fp32->bf16 + transpose: v (B,T,G,D) -> vt (B,G,D,T).
// ---------------------------------------------------------------------------
__global__ __launch_bounds__(256)
void v_cast_transpose(const float* __restrict__ v, u16* __restrict__ vt) {
    __shared__ u16 Lt[128 * 66];
    const int t  = threadIdx.x;
    const int t0 = blockIdx.x * 64;
    const int bg = blockIdx.y;
    const int b  = bg / NG, g = bg % NG;
#pragma unroll
    for (int rep = 0; rep < 8; ++rep) {
        int idx = rep * 256 + t;
        int i   = idx >> 5;
        int c   = idx & 31;
        float4 f = *(const float4*)(v + ((size_t)(b*T_SEQ + t0 + i)*NG + g)*DH + c*4);
        Lt[(c*4+0)*66 + i] = f2bf(f.x);
        Lt[(c*4+1)*66 + i] = f2bf(f.y);
        Lt[(c*4+2)*66 + i] = f2bf(f.z);
        Lt[(c*4+3)*66 + i] = f2bf(f.w);
    }
    __syncthreads();
#pragma unroll
    for (int rep = 0; rep < 4; ++rep) {
        int idx = rep * 256 + t;
        int d = idx >> 3, c = idx & 7;
        const u16* src = &Lt[d*66 + c*8];
        uint4 val;
        val.x = *(const unsigned int*)(src + 0);
        val.y = *(const unsigned int*)(src + 2);
        val.z = *(const unsigned int*)(src + 4);
        val.w = *(const unsigned int*)(src + 6);
        *(uint4*)(vt + ((size_t)(bg*DH + d))*T_SEQ + t0 + c*8) = val;
    }
}

// ---------------------------------------------------------------------------
// MFMA flash attention v10 = v6 structure (verified 80us) + in-register P,
// using ONLY the verified 16x16x32 MFMA builtin (v9 lesson: device-builtin
// availability can't be probed by preprocessor -- host pass says no).
//   S^T = mfma(A=K, B=Q): lane holds P[q=l15][4 keys per 16-key chunk].
//   K-rows are staged PERMUTED (per-lane global src addr; LDS dest linear):
//   within each 32-key block, LDS row r <- physical key
//   ((r>>2)&3)*8 + (r>>4)*4 + (r&3). Then the two chunk outputs of a 32-key
//   block concatenate IN-REGISTER into the exact K=32 PV A-fragment
//   (keys 8*quad..8*quad+7 in physical order), and the V B-fragment is the
//   SAME b128 read pattern v6 used. P never touches LDS: Ps deleted
//   (v6's 2.16M conflict cycles were P stores), LDS 72->64 KB.
// Kept: folded-log2e poly, diag-only mask, dim3(64,8) pairing, no setprio.
// ---------------------------------------------------------------------------
__global__ __launch_bounds__(256, 2)
void flash_attn_mfma(const u16* __restrict__ qh, const u16* __restrict__ kh,
                     const u16* __restrict__ vt, u16* __restrict__ y) {
    __shared__ __align__(16) u16 Ks[2][64*128];   // [buf][ldsrow][d] swizzled, rows permuted
    __shared__ __align__(16) u16 Vs[2][128*64];   // [buf][d][key]   swizzled

    const int t    = threadIdx.x;
    const int lane = t & 63, w = t >> 6;            // w = 0..3 = head-in-group
    const int l15  = lane & 15, quad = lane >> 4;
    const int bg   = blockIdx.y;
    const int b    = bg >> 2, g = bg & 3;
    const int chunk = b ? (int)blockIdx.x : (63 - (int)blockIdx.x);
    const int q0   = chunk * 32;
    const int h    = g * (NH / NG) + w;

    // tanh-poly coefficients pre-multiplied by log2(e)
    const float C0 =  1.4426950408889634f;
    const float C1 = -0.48089834696298777f;
    const float C2 =  0.19235933878519512f;
    const float C3 = -0.07785972536301652f;

    // Q fragments (MFMA B-operand: col=l15=q, k=quad*8.. -- same lane map as A)
    bf16x8 aq[2][4];
#pragma unroll
    for (int m = 0; m < 2; ++m) {
        const u16* qp = qh + ((size_t)(b*T_SEQ + q0 + m*16 + l15) * NH + h) * DH;
#pragma unroll
        for (int kc = 0; kc < 4; ++kc)
            aq[m][kc] = __builtin_bit_cast(bf16x8, *(const uint4*)(qp + kc*32 + quad*8));
    }

    f32x4 accO[2][8];           // [m][d-tile]: row=q=quad*4+r, col=d=l15
#pragma unroll
    for (int m = 0; m < 2; ++m)
#pragma unroll
        for (int nd = 0; nd < 8; ++nd) accO[m][nd] = (f32x4){0.f, 0.f, 0.f, 0.f};
    float ls[2] = {0.f, 0.f};   // per-lane partial row sum for q = l15

    const u16* kgb = kh + ((size_t)b*T_SEQ*NG + g)*DH;
    const u16* vgb = vt + ((size_t)(b*NG + g)*DH)*T_SEQ;

    // DMA staging roles (per thread, 4 passes each for K and V):
    // dest is LINEAR (wave-uniform base + lane*16); source carries swizzle+perm.
    const int krb = t >> 4, kcl = t & 15;
    const int vdb = t >> 3, vcl = t & 7;

    const int ktiles = q0/64 + 1;

    // prologue: stage tile 0 -> buf 0
#pragma unroll
    for (int j = 0; j < 4; ++j) {
        const int kr = j*16 + krb;                  // LDS row
        const int rp = kr & 31;
        const int kphys = (kr & 32) + ((rp >> 2) & 3)*8 + (rp >> 4)*4 + (rp & 3);
        gll16(kgb + (size_t)kphys*(NG*DH) + ((kcl ^ (kr & 7)) << 3),
              (char*)Ks[0] + j*4096 + w*1024);
        const int vd = j*32 + vdb;
        gll16(vgb + (size_t)vd*T_SEQ + ((vcl ^ (vd & 7)) << 3),
              (char*)Vs[0] + j*4096 + w*1024);
    }

    for (int kt = 0; kt < ktiles; ++kt) {
        asm volatile("s_waitcnt vmcnt(0)" ::: "memory");
        __syncthreads();

        if (kt + 1 < ktiles) {          // issue next-tile DMA, overlaps compute
            const int k0n = (kt + 1) * 64, bn = (kt + 1) & 1;
#pragma unroll
            for (int j = 0; j < 4; ++j) {
                const int kr = j*16 + krb;
                const int rp = kr & 31;
                const int kphys = (kr & 32) + ((rp >> 2) & 3)*8 + (rp >> 4)*4 + (rp & 3);
                gll16(kgb + (size_t)(k0n + kphys)*(NG*DH) + ((kcl ^ (kr & 7)) << 3),
                      (char*)Ks[bn] + j*4096 + w*1024);
                const int vd = j*32 + vdb;
                gll16(vgb + (size_t)vd*T_SEQ + k0n + ((vcl ^ (vd & 7)) << 3),
                      (char*)Vs[bn] + j*4096 + w*1024);
            }
        }

        const u16* Kb = Ks[kt & 1];
        const u16* Vb = Vs[kt & 1];
        const int k0 = kt * 64;
        const bool diag = (kt == ktiles - 1);

        // --- S^T = K Q^T per 16-row chunk; pack PV A-frags fully in-register.
        // LDS row (kc16*16 + quad*4 + r) holds physical key
        //   (kc16>>1)*32 + quad*8 + (kc16&1)*4 + r  (staging permutation),
        // so chunks (2b,2b+1) concatenate to keys 8q..8q+7 of block b.
        bf16x8 pa[2][2];                // [m][32-key block]
#pragma unroll
        for (int b32 = 0; b32 < 2; ++b32) {
            alignas(16) u16 pk0[8];
            alignas(16) u16 pk1[8];
#pragma unroll
            for (int sub = 0; sub < 2; ++sub) {
                const int kc16 = b32*2 + sub;
                const int krow = kc16*16 + l15;
                const int kswz = (krow & 7) << 3;
                f32x4 st0 = (f32x4){0.f,0.f,0.f,0.f};
                f32x4 st1 = (f32x4){0.f,0.f,0.f,0.f};
#pragma unroll
                for (int kc = 0; kc < 4; ++kc) {
                    bf16x8 ak = __builtin_bit_cast(bf16x8,
                        *(const uint4*)&Kb[krow*128 + ((kc*32 + quad*8) ^ kswz)]);
                    st0 = __builtin_amdgcn_mfma_f32_16x16x32_bf16(ak, aq[0][kc], st0, 0, 0, 0);
                    st1 = __builtin_amdgcn_mfma_f32_16x16x32_bf16(ak, aq[1][kc], st1, 0, 0, 0);
                }
                // lane: q = l15, physical key = k0 + b32*32 + quad*8 + sub*4 + r
#pragma unroll
                for (int m = 0; m < 2; ++m) {
                    const f32x4 st = m ? st1 : st0;
#pragma unroll
                    for (int r = 0; r < 4; ++r) {
                        float sv = st[r];
                        float z = sv * 0.02f;         // s/50
                        float u = z * z;
                        float poly = fmaf(u, fmaf(u, fmaf(u, C3, C2), C1), C0);
                        float pv = __builtin_amdgcn_exp2f(sv * poly);
                        if (diag) {
                            const int keyg = k0 + b32*32 + quad*8 + sub*4 + r;
                            const int qg   = q0 + m*16 + l15;
                            pv = (keyg > qg) ? 0.f : pv;
                        }
                        ls[m] += pv;
                        if (m) pk1[sub*4 + r] = f2bf(pv);
                        else   pk0[sub*4 + r] = f2bf(pv);
                    }
                }
            }
            pa[0][b32] = __builtin_bit_cast(bf16x8, *(const uint4*)pk0);
            pa[1][b32] = __builtin_bit_cast(bf16x8, *(const uint4*)pk1);
        }

        // --- O += P V via K=32: B-frag = Vt[d=nd*16+l15][keys b32*32+quad*8..]
        //     (identical b128 pattern to verified v6) ---
#pragma unroll
        for (int nd = 0; nd < 8; ++nd) {
            const int vrow = nd*16 + l15;
            const int vswz = (vrow & 7) << 3;
#pragma unroll
            for (int b32 = 0; b32 < 2; ++b32) {
                bf16x8 bv = __builtin_bit_cast(bf16x8,
                    *(const uint4*)&Vb[vrow*64 + ((b32*32 + quad*8) ^ vswz)]);
                accO[0][nd] = __builtin_amdgcn_mfma_f32_16x16x32_bf16(pa[0][b32], bv, accO[0][nd], 0, 0, 0);
                accO[1][nd] = __builtin_amdgcn_mfma_f32_16x16x32_bf16(pa[1][b32], bv, accO[1][nd], 0, 0, 0);
            }
        }
    }

    // --- row sums: reduce across quads (q = l15), then redistribute ---
#pragma unroll
    for (int m = 0; m < 2; ++m) {
        float v = ls[m];
        v += __shfl_xor(v, 16, 64);
        v += __shfl_xor(v, 32, 64);
        ls[m] = v;                      // total for q = l15 (uniform over quads)
    }

#pragma unroll
    for (int m = 0; m < 2; ++m)
#pragma unroll
        for (int r = 0; r < 4; ++r) {
            const float invl = 1.f / __shfl(ls[m], quad*4 + r, 64);
            u16* yp = y + (size_t)(b*T_SEQ + q0 + m*16 + quad*4 + r) * C_DIM + h*DH;
#pragma unroll
            for (int nd = 0; nd < 8; ++nd)
                yp[nd*16 + l15] = f2bf(accO[m][nd][r] * invl);
        }
}

// ---------------------------------------------------------------------------
extern "C" void kernel_launch(void* const* d_in, const int* in_sizes, int n_in,
                              void* d_out, int out_size, void* d_ws, size_t ws_size,
                              hipStream_t stream) {
    const float* x  = (const float*)d_in[0];
    const float* Wq = (const float*)d_in[1];
    const float* Wk = (const float*)d_in[2];
    const float* Wv = (const float*)d_in[3];
    const float* Wo = (const float*)d_in[4];
    const float* bo = (const float*)d_in[5];
    const float* qw = (const float*)d_in[6];
    const float* kw = (const float*)d_in[7];
    float* out = (float*)d_out;

    const size_t qE = (size_t)BATCH * T_SEQ * NH * DH;   // 8,388,608
    const size_t kE = (size_t)BATCH * T_SEQ * NG * DH;   // 2,097,152
    const size_t wqE = (size_t)C_DIM * C_DIM;            // 4,194,304
    const size_t wkE = (size_t)(NG*DH) * C_DIM;          // 1,048,576

    float* qf  = (float*)d_ws;          // qE floats
    float* kf  = qf + qE;               // kE floats
    float* vf  = kf + kE;               // kE floats
    u16*   qh  = (u16*)(vf + kE);       // qE
    u16*   khb = qh + qE;               // kE
    u16*   vtb = khb + kE;              // kE
    u16*   xh  = vtb + kE;              // qE
    u16*   wqh = xh + qE;               // wqE
    u16*   wkh = wqh + wqE;             // wkE
    u16*   wvh = wkh + wkE;             // wkE
    float* cosT = (float*)(wvh + wkE);  // 131072 floats
    float* sinT = cosT + 131072;        // 131072 floats
    u16*   woh = (u16*)kf;              // wqE (reuses kf: dead after rmsnorm)
    u16*   yh  = (u16*)qf;              // qE  (reuses qf: dead after rmsnorm)

    const int M = BATCH * T_SEQ;   // 4096
    dim3 blk(256);

    rope_tables<<<dim3(512), blk, 0, stream>>>(cosT, sinT);

    cast_multi<<<dim3(7168), blk, 0, stream>>>(x, Wq, Wk, Wv, xh, wqh, wkh, wvh);

    gemm_qkv<<<dim3(24, M/128), blk, 0, stream>>>(xh, wqh, wkh, wvh, qf, kf, vf);

    rmsnorm_rope_qk<<<dim3(M*NH/4 + M*NG/4), blk, 0, stream>>>(qf, kf, qw, kw, cosT, sinT, qh, khb);
    v_cast_transpose<<<dim3(T_SEQ/64, BATCH*NG), blk, 0, stream>>>(vf, vtb);

    cast_f32_bf16<<<dim3(wqE/8/256), blk, 0, stream>>>(Wo, woh, wqE/8);

    flash_attn_mfma<<<dim3(T_SEQ/32, BATCH*NG), blk, 0, stream>>>(qh, khb, vtb, yh);

    gemm_nt_bf16<<<dim3(C_DIM/128, M/128), blk, 0, stream>>>(yh, woh, bo, out, C_DIM, C_DIM);
}